// Round 1
// baseline (357.484 us; speedup 1.0000x reference)
//
#include <hip/hip_runtime.h>

// MatrixKAN as dense bf16 MFMA GEMM over expanded interpolation basis.
// K layout: per feature i, 24 slots: [0..20]=hat weights (2 nonzero), 21=silu(xc), 22..23=pad.
// out[b,o] = sum_k A[b,k] * W_aug[o,k]   (fp32 accum, K-split 2 with atomicAdd epilogue)

typedef short v8s __attribute__((ext_vector_type(8)));
typedef float v4f __attribute__((ext_vector_type(4)));

#define B_DIM 8192
#define IN_DIM 512
#define OUT_DIM 512
#define G_DIM 20
#define SLOTS 24
#define K_DIM (IN_DIM * SLOTS)     // 12288
#define BM 128
#define BN 128
#define BK 96                      // 4 features per K-tile
#define KT_TOTAL (K_DIM / BK)      // 128
#define KSPLIT 2
#define KT_PER (KT_TOTAL / KSPLIT) // 64
#define AROW 256                   // LDS bytes per tile row (12 used chunks of 16B, XOR-swizzled in 16)

static __device__ __forceinline__ unsigned f2bf(float f) {
  unsigned u = __builtin_bit_cast(unsigned, f);
  return (u + 0x7fffu + ((u >> 16) & 1u)) >> 16;   // RNE bf16
}

__global__ void zero_out_kernel(uint4* __restrict__ out) {
  out[(size_t)blockIdx.x * 256 + threadIdx.x] = uint4{0u, 0u, 0u, 0u};
}

// x[b][i] (fp32) -> P[i][b] packed {bf16 1-t, bf16 t, bf16 silu, u16 idx}, LDS-transposed for coalescing
__global__ void pack_kernel(const float* __restrict__ x, uint2* __restrict__ P) {
  __shared__ uint2 tile[64 * 65];
  const int b0 = blockIdx.x * 64;
  const int i0 = blockIdx.y * 64;
  const int t = threadIdx.x;
  const int tr = t >> 6;
  const int tc = t & 63;
#pragma unroll
  for (int it = 0; it < 16; ++it) {
    int br = it * 4 + tr;
    float xv = x[(size_t)(b0 + br) * IN_DIM + i0 + tc];
    float xc = fminf(fmaxf(xv, -1.0f), 1.0f);
    float xg = (xc + 1.0f) * 10.0f;           // (xc+1)*0.5*G
    int idx = (int)floorf(xg);
    idx = idx < 0 ? 0 : (idx > G_DIM - 1 ? G_DIM - 1 : idx);
    float tt = xg - (float)idx;
    float sl = xc / (1.0f + __expf(-xc));     // silu(clipped x)
    uint2 pv;
    pv.x = f2bf(1.0f - tt) | (f2bf(tt) << 16);
    pv.y = f2bf(sl) | ((unsigned)idx << 16);
    tile[tc * 65 + br] = pv;
  }
  __syncthreads();
#pragma unroll
  for (int it = 0; it < 16; ++it) {
    int ir = it * 4 + tr;
    P[(size_t)(i0 + ir) * B_DIM + b0 + tc] = tile[ir * 65 + tc];
  }
}

// coeffs[o][i][21] + base_w[o][i] -> W_aug bf16 [o][i*24 + slot]
__global__ void wpack_kernel(const float* __restrict__ coeffs,
                             const float* __restrict__ base_w,
                             unsigned short* __restrict__ W) {
  int g = blockIdx.x * 256 + threadIdx.x;   // o*512 + i
  const float* c = coeffs + (size_t)g * 21;
  float cf[21];
#pragma unroll
  for (int j = 0; j < 21; ++j) cf[j] = c[j];
  float bw = base_w[g];
  unsigned d[12];
#pragma unroll
  for (int j = 0; j < 10; ++j) d[j] = f2bf(cf[2 * j]) | (f2bf(cf[2 * j + 1]) << 16);
  d[10] = f2bf(cf[20]) | (f2bf(bw) << 16);  // slots 20, 21(=base_w)
  d[11] = 0u;                               // slots 22, 23 pad
  int o = g >> 9, i = g & 511;
  uint4* dst = (uint4*)(W + (size_t)o * K_DIM + i * SLOTS);
  dst[0] = uint4{d[0], d[1], d[2], d[3]};
  dst[1] = uint4{d[4], d[5], d[6], d[7]};
  dst[2] = uint4{d[8], d[9], d[10], d[11]};
}

// swizzled LDS address helper: row-major tile, 256B rows, chunk' = chunk ^ (row&7)
static __device__ __forceinline__ char* swz(char* base, int row, int slot) {
  return base + row * AROW + ((((slot >> 3) ^ (row & 7)) << 4) + ((slot & 7) << 1));
}

__global__ __launch_bounds__(256, 2) void kan_gemm(const uint2* __restrict__ P,
                                                   const unsigned short* __restrict__ W,
                                                   float* __restrict__ out) {
  __shared__ uint4 lds4[(BM * AROW + BN * AROW) / 16];   // 32KB A + 32KB B
  char* Ab = (char*)lds4;
  char* Bb = (char*)lds4 + BM * AROW;
  const int t = threadIdx.x;
  const int lane = t & 63;
  const int wv = t >> 6;               // 4 waves, 2x2 grid of 64x64 tiles
  const int wm = wv >> 1, wn = wv & 1;
  const int b0 = blockIdx.x * BM;
  const int n0 = blockIdx.y * BN;
  const int kt0 = blockIdx.z * KT_PER;

  // zero the A tile once (pads + untouched slots stay zero forever)
#pragma unroll
  for (int j = 0; j < 32; ++j) ((unsigned*)Ab)[t + 256 * j] = 0u;

  v4f acc[4][4];
  const v4f z4 = {0.f, 0.f, 0.f, 0.f};
#pragma unroll
  for (int ii = 0; ii < 4; ++ii)
#pragma unroll
    for (int jj = 0; jj < 4; ++jj) acc[ii][jj] = z4;

  const int arow = t & 127;            // A-gen: this thread owns (row=arow, features f0,f0+1)
  const int f0 = (t >> 7) * 2;
  int pidx0 = 0, pidx1 = 0;
  const int brow = t >> 1;             // B-stage: row 0..127, 6 of 12 chunks per thread
  const int cb = (t & 1) * 6;

  for (int kt = kt0; kt < kt0 + KT_PER; ++kt) {
    const int i0 = kt * 4;
    const size_t k0 = (size_t)kt * BK;
    // global loads (in flight across sync1 / A-gen)
    uint2 pv0 = P[(size_t)(i0 + f0) * B_DIM + b0 + arow];
    uint2 pv1 = P[(size_t)(i0 + f0 + 1) * B_DIM + b0 + arow];
    uint4 bv[6];
#pragma unroll
    for (int q = 0; q < 6; ++q)
      bv[q] = *(const uint4*)(W + (size_t)(n0 + brow) * K_DIM + k0 + (cb + q) * 8);

    __syncthreads();   // previous compute done; safe to overwrite tiles

    // stage B (swizzled ds_write_b128)
#pragma unroll
    for (int q = 0; q < 6; ++q) {
      int c = cb + q;
      *(uint4*)(Bb + brow * AROW + (((c ^ (brow & 7)) << 4))) = bv[q];
    }
    // generate A: clear last iter's 2 slots, write 1-t/t at idx/idx+1, silu at slot 21
    {
      int base = f0 * SLOTS;
      *(unsigned short*)swz(Ab, arow, base + pidx0) = 0;
      *(unsigned short*)swz(Ab, arow, base + pidx0 + 1) = 0;
      int idx = (int)(pv0.y >> 16);
      *(unsigned short*)swz(Ab, arow, base + idx) = (unsigned short)(pv0.x & 0xffffu);
      *(unsigned short*)swz(Ab, arow, base + idx + 1) = (unsigned short)(pv0.x >> 16);
      *(unsigned short*)swz(Ab, arow, base + 21) = (unsigned short)(pv0.y & 0xffffu);
      pidx0 = idx;
    }
    {
      int base = (f0 + 1) * SLOTS;
      *(unsigned short*)swz(Ab, arow, base + pidx1) = 0;
      *(unsigned short*)swz(Ab, arow, base + pidx1 + 1) = 0;
      int idx = (int)(pv1.y >> 16);
      *(unsigned short*)swz(Ab, arow, base + idx) = (unsigned short)(pv1.x & 0xffffu);
      *(unsigned short*)swz(Ab, arow, base + idx + 1) = (unsigned short)(pv1.x >> 16);
      *(unsigned short*)swz(Ab, arow, base + 21) = (unsigned short)(pv1.y & 0xffffu);
      pidx1 = idx;
    }
    __syncthreads();

    // compute: 3 K32-steps, 16 MFMA each per wave
    const int r16 = lane & 15;
    const int q16 = lane >> 4;
#pragma unroll
    for (int s = 0; s < 3; ++s) {
      const int chunk = s * 4 + q16;   // k = chunk*8 + j
      v8s af[4], bfr[4];
#pragma unroll
      for (int rm = 0; rm < 4; ++rm) {
        int row = wm * 64 + rm * 16 + r16;
        af[rm] = *(const v8s*)(Ab + row * AROW + ((chunk ^ (row & 7)) << 4));
      }
#pragma unroll
      for (int cn = 0; cn < 4; ++cn) {
        int row = wn * 64 + cn * 16 + r16;
        bfr[cn] = *(const v8s*)(Bb + row * AROW + ((chunk ^ (row & 7)) << 4));
      }
#pragma unroll
      for (int rm = 0; rm < 4; ++rm)
#pragma unroll
        for (int cn = 0; cn < 4; ++cn)
          acc[rm][cn] = __builtin_amdgcn_mfma_f32_16x16x32_bf16(af[rm], bfr[cn], acc[rm][cn], 0, 0, 0);
    }
  }

  // epilogue: C/D layout col=lane&15, row=(lane>>4)*4+reg (verified m89/m91)
  const int r16 = lane & 15;
  const int q4 = (lane >> 4) * 4;
#pragma unroll
  for (int rm = 0; rm < 4; ++rm)
#pragma unroll
    for (int cn = 0; cn < 4; ++cn)
#pragma unroll
      for (int r = 0; r < 4; ++r) {
        int row = b0 + wm * 64 + rm * 16 + q4 + r;
        int col = n0 + wn * 64 + cn * 16 + r16;
        atomicAdd(out + (size_t)row * OUT_DIM + col, acc[rm][cn][r]);
      }
}

extern "C" void kernel_launch(void* const* d_in, const int* in_sizes, int n_in,
                              void* d_out, int out_size, void* d_ws, size_t ws_size,
                              hipStream_t stream) {
  const float* x = (const float*)d_in[0];
  const float* coeffs = (const float*)d_in[1];
  const float* base_w = (const float*)d_in[2];
  float* out = (float*)d_out;

  uint2* P = (uint2*)d_ws;                                              // 33.55 MB
  unsigned short* W = (unsigned short*)((char*)d_ws +
                      (size_t)IN_DIM * B_DIM * sizeof(uint2));          // +12.58 MB

  zero_out_kernel<<<(B_DIM * OUT_DIM) / 1024, 256, 0, stream>>>((uint4*)out);
  pack_kernel<<<dim3(B_DIM / 64, IN_DIM / 64), 256, 0, stream>>>(x, P);
  wpack_kernel<<<(OUT_DIM * IN_DIM) / 256, 256, 0, stream>>>(coeffs, base_w, W);
  kan_gemm<<<dim3(B_DIM / BM, OUT_DIM / BN, KSPLIT), 256, 0, stream>>>(P, W, out);
}